// Round 10
// baseline (159.324 us; speedup 1.0000x reference)
//
#include <hip/hip_runtime.h>

typedef __attribute__((ext_vector_type(8))) short bf16x8;
typedef __attribute__((ext_vector_type(4))) float f32x4;
typedef __attribute__((ext_vector_type(4))) unsigned uint4v;

#define SM_C 0.18033688011112042f  // 0.125 * log2(e)
#define MFMA16 __builtin_amdgcn_mfma_f32_16x16x32_bf16

__device__ __forceinline__ unsigned short f2bf(float f) {
  unsigned u = __builtin_bit_cast(unsigned, f);
  u += 0x7fffu + ((u >> 16) & 1u);
  return (unsigned short)(u >> 16);
}

__device__ __forceinline__ unsigned cvtpk(float lo, float hi) {
  unsigned r;
  asm volatile("v_cvt_pk_bf16_f32 %0, %1, %2" : "=v"(r) : "v"(lo), "v"(hi));
  return r;
}

__device__ __forceinline__ void gload16(const void* g, void* lds) {
  __builtin_amdgcn_global_load_lds(
      (const __attribute__((address_space(1))) void*)g,
      (__attribute__((address_space(3))) void*)lds, 16, 0, 0);
}

#define BARRIER __builtin_amdgcn_s_barrier()
#define ABARRIER asm volatile("s_barrier" ::: "memory")
#define LGKM0 asm volatile("s_waitcnt lgkmcnt(0)" ::: "memory")

// ---------------- x -> bf16 ----------------
__global__ __launch_bounds__(256) void cvt_x(const float* __restrict__ in,
                                             unsigned short* __restrict__ out,
                                             int n4) {
  int i = blockIdx.x * 256 + threadIdx.x;
  int stride = gridDim.x * 256;
  for (; i < n4; i += stride) {
    float4 v = ((const float4*)in)[i];
    unsigned short o0 = f2bf(v.x), o1 = f2bf(v.y), o2 = f2bf(v.z), o3 = f2bf(v.w);
    unsigned long long packed = (unsigned long long)o0 | ((unsigned long long)o1 << 16) |
                                ((unsigned long long)o2 << 32) | ((unsigned long long)o3 << 48);
    ((unsigned long long*)out)[i] = packed;
  }
}

// ---------------- 4x W[K][N] f32 -> WT[N][K] bf16 (fused) ----------------
__global__ __launch_bounds__(256) void transpose_w4(const float* __restrict__ W0,
                                                    const float* __restrict__ W1,
                                                    const float* __restrict__ W2,
                                                    const float* __restrict__ W3,
                                                    unsigned short* __restrict__ WT) {
  __shared__ float tile[32][33];
  const int z = blockIdx.z;
  const float* W = (z == 0) ? W0 : (z == 1) ? W1 : (z == 2) ? W2 : W3;
  unsigned short* WTo = WT + (size_t)z * 1048576;
  int bx = blockIdx.x, by = blockIdx.y;
  int x = bx * 32 + threadIdx.x;
  for (int i = 0; i < 4; ++i) {
    int r = threadIdx.y + i * 8;
    tile[r][threadIdx.x] = W[(by * 32 + r) * 1024 + x];
  }
  __syncthreads();
  int nx = by * 32 + threadIdx.x;
  for (int i = 0; i < 4; ++i) {
    int r = threadIdx.y + i * 8;
    WTo[(long)(bx * 32 + r) * 1024 + nx] = f2bf(tile[threadIdx.x][r]);
  }
}

// ---------------- V columns of QKV -> Vt[bh][hd][s_perm] ----------------
__global__ __launch_bounds__(256) void transpose_v(const unsigned short* __restrict__ QKV,
                                                   unsigned short* __restrict__ Vt) {
  __shared__ alignas(16) unsigned short tile[64][74];
  const int bid = blockIdx.x;
  const int st = bid & 31, bh = bid >> 5;
  const int b = bh >> 4, h = bh & 15;
  const int t = threadIdx.x;
  const int r = t >> 2, c16 = (t & 3) * 16;
  const unsigned short* src =
      QKV + ((long)(b * 2048 + st * 64 + r)) * 3072 + 2048 + h * 64 + c16;
  uint4v v0 = *(const uint4v*)src;
  uint4v v1 = *(const uint4v*)(src + 8);
  unsigned* dst32 = (unsigned*)&tile[r][c16];
  dst32[0] = v0[0]; dst32[1] = v0[1]; dst32[2] = v0[2]; dst32[3] = v0[3];
  dst32[4] = v1[0]; dst32[5] = v1[1]; dst32[6] = v1[2]; dst32[7] = v1[3];
  __syncthreads();
  const int lw = t & 63, w = t >> 6;
  const int vp = (lw & 32) | (((lw >> 2) & 3) << 3) | (((lw >> 4) & 1) << 2) | (lw & 3);
#pragma unroll
  for (int k = 0; k < 16; ++k) {
    int hd = w * 16 + k;
    Vt[((long)(bh * 64 + hd)) * 2048 + st * 64 + vp] = tile[lw][hd];
  }
}

// ---------------- GEMM v6: A triple-buffer, B double-buffer, 1 vmcnt/K-tile -
template <int NR, int FP32OUT>
__global__ __launch_bounds__(512, 1) void gemm3b(const unsigned short* __restrict__ A,
                                                 const unsigned short* __restrict__ BT,
                                                 unsigned short* __restrict__ Cb,
                                                 float* __restrict__ Cf,
                                                 const float* __restrict__ bias,
                                                 int M, int N, int K) {
  constexpr int BN = NR * 64;
  __shared__ alignas(16) unsigned short As[3][256 * 64];
  __shared__ alignas(16) unsigned short Bs[2][BN * 64];

  const int nbn = N / BN;
  const int tmg = (M / 256) / 8;
  const int cc = blockIdx.x >> 3, xc = blockIdx.x & 7;
  const int tm = xc * tmg + cc / nbn, tn = cc % nbn;

  const int t = threadIdx.x, l = t & 63, wid = t >> 6;
  const int wm = wid >> 2, wn = wid & 3;
  const int lr = l & 15, lg = l >> 4;

  f32x4 acc[8][NR] = {};

  const int sq = t >> 3;
  const int sslot8 = ((t & 7) ^ (sq & 7)) * 8;
  const unsigned short* Ath = A + ((long)tm * 256 + sq) * K + sslot8;
  const unsigned short* Bth = BT + ((long)tn * BN + sq) * K + sslot8;
  const int ldsoff = sq * 64 + (t & 7) * 8;

#define STGA(buf, q, kt) \
  gload16(Ath + (long)((q)*64) * K + (kt)*64, &As[buf][(q)*4096 + ldsoff])
#define STGB(buf, u, kt) \
  gload16(Bth + (long)((u)*64) * K + (kt)*64, &Bs[buf][(u)*4096 + ldsoff])

  const int NT = K >> 6;
#pragma unroll
  for (int q = 0; q < 4; ++q) STGA(0, q, 0);
#pragma unroll
  for (int u = 0; u < NR; ++u) STGB(0, u, 0);
#pragma unroll
  for (int q = 0; q < 4; ++q) STGA(1, q, 1);

  const int offk0 = (lg ^ (lr & 7)) * 8;
  const int offk1 = ((4 + lg) ^ (lr & 7)) * 8;
  const int arow0 = (wm * 128 + lr) * 64;
  const int brow0 = (wn * (NR * 16) + lr) * 64;

#define DS_A(MH)                                                   \
  _Pragma("unroll") for (int m_ = 0; m_ < 4; ++m_) {               \
    const unsigned short* ap_ = Ac + arow0 + ((MH)*4 + m_) * 1024; \
    af[m_][0] = *(const bf16x8*)(ap_ + offk0);                     \
    af[m_][1] = *(const bf16x8*)(ap_ + offk1);                     \
  }
#define DS_B_ALL                                          \
  _Pragma("unroll") for (int n_ = 0; n_ < NR; ++n_) {     \
    const unsigned short* bp_ = Bc + brow0 + n_ * 1024;   \
    bfr[n_][0] = *(const bf16x8*)(bp_ + offk0);           \
    bfr[n_][1] = *(const bf16x8*)(bp_ + offk1);           \
  }
#define MM(MH)                                                              \
  __builtin_amdgcn_s_setprio(1);                                            \
  _Pragma("unroll") for (int m_ = 0; m_ < 4; ++m_)                          \
  _Pragma("unroll") for (int n_ = 0; n_ < NR; ++n_) {                       \
    acc[(MH)*4 + m_][n_] = MFMA16(af[m_][0], bfr[n_][0],                    \
                                  acc[(MH)*4 + m_][n_], 0, 0, 0);           \
    acc[(MH)*4 + m_][n_] = MFMA16(af[m_][1], bfr[n_][1],                    \
                                  acc[(MH)*4 + m_][n_], 0, 0, 0);           \
  }                                                                         \
  __builtin_amdgcn_s_setprio(0);

  int cur3 = 0;
  int stg3 = 2;
  for (int tt = 0; tt < NT; ++tt) {
    const unsigned short* Ac = As[cur3];
    const unsigned short* Bc = Bs[tt & 1];

    bf16x8 af[4][2];
    bf16x8 bfr[NR][2];

    if (tt == NT - 1) asm volatile("s_waitcnt vmcnt(0)" ::: "memory");
    else              asm volatile("s_waitcnt vmcnt(4)" ::: "memory");
    BARRIER;
    DS_A(0);
    DS_B_ALL;
    if (tt + 1 < NT) {
      const int nbB = (tt + 1) & 1;
#pragma unroll
      for (int u = 0; u < NR; ++u) STGB(nbB, u, tt + 1);
    }
    BARRIER;
    LGKM0;
    MM(0);

    DS_A(1);
    if (tt + 2 < NT) {
#pragma unroll
      for (int q = 0; q < 4; ++q) STGA(stg3, q, tt + 2);
    }
    BARRIER;
    LGKM0;
    MM(1);

    cur3 = (cur3 == 2) ? 0 : cur3 + 1;
    stg3 = (stg3 == 2) ? 0 : stg3 + 1;
  }
#undef DS_A
#undef DS_B_ALL
#undef MM
#undef STGA
#undef STGB

  const long crow = (long)tm * 256 + wm * 128;
  const int ccol = tn * BN + wn * (NR * 16);
#pragma unroll
  for (int m = 0; m < 8; ++m)
#pragma unroll
    for (int n = 0; n < NR; ++n)
#pragma unroll
      for (int r = 0; r < 4; ++r) {
        long row = crow + m * 16 + lg * 4 + r;
        int col = ccol + n * 16 + lr;
        if (FP32OUT)
          Cf[row * N + col] = acc[m][n][r] + bias[col];
        else
          Cb[row * N + col] = f2bf(acc[m][n][r]);
      }
}

// ---------------- Flash attention tile body ----------------
template <int TWO>
__device__ __forceinline__ void attn_tile(
    const unsigned short* __restrict__ Kc, const unsigned short* __restrict__ Vc,
    int lr, int lg, bool mask0, bool mask1, int kv0, int q0row, int q1row,
    const bf16x8 (&qf)[2][2], f32x4 (&cacc)[2][4], float (&m_r)[2], float (&l_r)[2]) {
  constexpr int S0 = TWO ? 0 : 1;
  f32x4 p[2][4];
#pragma unroll
  for (int s = S0; s < 2; ++s)
#pragma unroll
    for (int g = 0; g < 4; ++g) p[s][g] = f32x4{0.f, 0.f, 0.f, 0.f};

  __builtin_amdgcn_s_setprio(1);
#pragma unroll
  for (int g = 0; g < 4; ++g) {
    const int key = g * 16 + lr;
    const int swz = (key & 7) << 3;
#pragma unroll
    for (int c = 0; c < 2; ++c) {
      bf16x8 kf = *(const bf16x8*)(Kc + key * 64 + ((c * 32 + lg * 8) ^ swz));
#pragma unroll
      for (int s = S0; s < 2; ++s)
        p[s][g] = MFMA16(kf, qf[s][c], p[s][g], 0, 0, 0);
    }
  }
  __builtin_amdgcn_s_setprio(0);

  if (TWO && mask0) {
#pragma unroll
    for (int g = 0; g < 4; ++g)
#pragma unroll
      for (int r = 0; r < 4; ++r)
        if (kv0 + g * 16 + lg * 4 + r > q0row) p[0][g][r] = -1e30f;
  }
  if (mask1) {
#pragma unroll
    for (int g = 0; g < 4; ++g)
#pragma unroll
      for (int r = 0; r < 4; ++r)
        if (kv0 + g * 16 + lg * 4 + r > q1row) p[1][g][r] = -1e30f;
  }

  unsigned pk[2][4][2];
#pragma unroll
  for (int s = S0; s < 2; ++s) {
    float mloc = p[s][0][0];
#pragma unroll
    for (int g = 0; g < 4; ++g)
#pragma unroll
      for (int r = 0; r < 4; ++r) mloc = fmaxf(mloc, p[s][g][r]);
    mloc = fmaxf(mloc, __shfl_xor(mloc, 16));
    mloc = fmaxf(mloc, __shfl_xor(mloc, 32));
    const bool defer = __all(mloc <= m_r[s] + 44.0f);
    const float mn = defer ? m_r[s] : fmaxf(m_r[s], mloc);
    const float nmc = -mn * SM_C;
    float rs = 0.f;
#pragma unroll
    for (int g = 0; g < 4; ++g)
#pragma unroll
      for (int r = 0; r < 4; ++r) {
        float e = __builtin_amdgcn_exp2f(__builtin_fmaf(p[s][g][r], SM_C, nmc));
        p[s][g][r] = e;
        rs += e;
      }
    rs += __shfl_xor(rs, 16);
    rs += __shfl_xor(rs, 32);
    if (defer) {
      l_r[s] += rs;
    } else {
      float alpha = __builtin_amdgcn_exp2f((m_r[s] - mn) * SM_C);
      l_r[s] = l_r[s] * alpha + rs;
      m_r[s] = mn;
      float alq[4];
#pragma unroll
      for (int r = 0; r < 4; ++r) alq[r] = __shfl(alpha, lg * 20 + r);
#pragma unroll
      for (int n = 0; n < 4; ++n)
#pragma unroll
        for (int r = 0; r < 4; ++r) cacc[s][n][r] *= alq[r];
    }
#pragma unroll
    for (int g = 0; g < 4; ++g) {
      pk[s][g][0] = cvtpk(p[s][g][0], p[s][g][1]);
      pk[s][g][1] = cvtpk(p[s][g][2], p[s][g][3]);
    }
  }

#pragma unroll
  for (int sl = 0; sl < 2; ++sl) {
    bf16x8 vf[4];
#pragma unroll
    for (int n = 0; n < 4; ++n) {
      const int hd = n * 16 + lr;
      vf[n] = *(const bf16x8*)(Vc + hd * 64 + ((sl * 32 + lg * 8) ^ ((hd & 7) << 3)));
    }
    __builtin_amdgcn_s_setprio(1);
#pragma unroll
    for (int s = S0; s < 2; ++s) {
      uint4v pw = {pk[s][2 * sl][0], pk[s][2 * sl][1], pk[s][2 * sl + 1][0], pk[s][2 * sl + 1][1]};
      bf16x8 pa = __builtin_bit_cast(bf16x8, pw);
#pragma unroll
      for (int n = 0; n < 4; ++n)
        cacc[s][n] = MFMA16(pa, vf[n], cacc[s][n], 0, 0, 0);
    }
    __builtin_amdgcn_s_setprio(0);
  }
}

// ---------------- Flash attention (paired strips, counted-vmcnt pipeline) ---
// Per KV-tile j: [vmcnt(4) (last: 0)][BAR] compute(j) [BAR] STAGE(j+2).
// KV(j)'s 4 loads are issued 2 tiles ahead; entry vmcnt(4) retires exactly
// them (outstanding = KV(j)+KV(j+1)).  Stage into buf[j&1] is sealed by the
// post-compute barrier (each wave's ds_reads retire via lgkm before MFMAs).
__global__ __launch_bounds__(256, 4) void flash_attn(const unsigned short* __restrict__ QKV,
                                                     const unsigned short* __restrict__ Vt,
                                                     unsigned short* __restrict__ Ctx) {
  __shared__ alignas(16) unsigned short Ks[2][64 * 64];
  __shared__ alignas(16) unsigned short Vs[2][64 * 64];
  const int bid = blockIdx.x;
  const int qt = bid >> 6;
  const int bh = bid & 63;
  const int b = bh >> 4, h = bh & 15;
  const int t = threadIdx.x, l = t & 63, w = t >> 6;
  const int lr = l & 15, lg = l >> 4;
  const long rowbase = (long)b * 2048;
  const int colbase = h * 64;
  const int q0 = qt * 64 + w * 16;
  const int q1 = (31 - qt) * 64 + w * 16;
  const int q0row = q0 + lr, q1row = q1 + lr;
  const int nkv = 32 - qt;

  bf16x8 qf[2][2];
#pragma unroll
  for (int c = 0; c < 2; ++c) {
    qf[0][c] = *(const bf16x8*)(QKV + (rowbase + q0 + lr) * 3072 + colbase + c * 32 + lg * 8);
    qf[1][c] = *(const bf16x8*)(QKV + (rowbase + q1 + lr) * 3072 + colbase + c * 32 + lg * 8);
  }

  f32x4 cacc[2][4];
  float m_r[2], l_r[2];
#pragma unroll
  for (int s = 0; s < 2; ++s) {
    m_r[s] = -1e30f;
    l_r[s] = 0.f;
#pragma unroll
    for (int n = 0; n < 4; ++n) cacc[s][n] = f32x4{0.f, 0.f, 0.f, 0.f};
  }

  const int srow = w * 16 + (l >> 3);
  const int scol = (l & 7) * 8;
  const int kswz = scol ^ ((srow & 7) << 3);
  const unsigned short* kp = QKV + (rowbase + srow) * 3072 + 1024 + colbase + kswz;
  const unsigned short* vp = Vt + ((long)(bh * 64 + srow)) * 2048 + kswz;
  unsigned short* ksd0 = &Ks[0][(w * 16) * 64];
  unsigned short* vsd0 = &Vs[0][(w * 16) * 64];

#define STAGE(buf)                                    \
  do {                                                \
    gload16(kp, ksd0 + (buf) * 4096);                 \
    gload16(kp + 8 * 3072, ksd0 + (buf) * 4096 + 512);\
    gload16(vp, vsd0 + (buf) * 4096);                 \
    gload16(vp + 8 * 2048, vsd0 + (buf) * 4096 + 512);\
    kp += 64 * 3072;                                  \
    vp += 64;                                         \
  } while (0)

#define TILE_WAIT(j)                                                          \
  do {                                                                        \
    if ((j) == nkv - 1) asm volatile("s_waitcnt vmcnt(0)" ::: "memory");      \
    else                asm volatile("s_waitcnt vmcnt(4)" ::: "memory");      \
    asm volatile("s_barrier" ::: "memory");                                   \
  } while (0)

  STAGE(0);
  STAGE(1);

  int j = 0;
  for (; j <= qt; ++j) {  // both strips active
    const int cur = j & 1;
    TILE_WAIT(j);
    attn_tile<1>(Ks[cur], Vs[cur], lr, lg, j == qt, false, j * 64, q0row, q1row,
                 qf, cacc, m_r, l_r);
    asm volatile("s_barrier" ::: "memory");
    if (j + 2 < nkv) STAGE(cur);
  }
  for (; j < nkv; ++j) {  // long strip only
    const int cur = j & 1;
    TILE_WAIT(j);
    attn_tile<0>(Ks[cur], Vs[cur], lr, lg, false, j == nkv - 1, j * 64, q0row, q1row,
                 qf, cacc, m_r, l_r);
    asm volatile("s_barrier" ::: "memory");
    if (j + 2 < nkv) STAGE(cur);
  }
#undef STAGE
#undef TILE_WAIT

#pragma unroll
  for (int s = 0; s < 2; ++s) {
    float invl = 1.f / l_r[s];
    float ilq[4];
#pragma unroll
    for (int r = 0; r < 4; ++r) ilq[r] = __shfl(invl, lg * 20 + r);
    const int qs = (s == 0) ? q0 : q1;
#pragma unroll
    for (int n = 0; n < 4; ++n)
#pragma unroll
      for (int r = 0; r < 4; ++r) {
        long row = rowbase + qs + lg * 4 + r;
        Ctx[row * 1024 + colbase + n * 16 + lr] = f2bf(cacc[s][n][r] * ilq[r]);
      }
  }
}

extern "C" void kernel_launch(void* const* d_in, const int* in_sizes, int n_in,
                              void* d_out, int out_size, void* d_ws, size_t ws_size,
                              hipStream_t stream) {
  (void)in_sizes; (void)n_in; (void)out_size; (void)ws_size;
  const float* x  = (const float*)d_in[0];
  const float* Wq = (const float*)d_in[1];
  const float* Wk = (const float*)d_in[2];
  const float* Wv = (const float*)d_in[3];
  const float* Wo = (const float*)d_in[4];
  const float* bo = (const float*)d_in[5];
  float* out = (float*)d_out;

  unsigned short* ws = (unsigned short*)d_ws;
  unsigned short* xb  = ws;                       // 8192*1024 (dead after QKV GEMM)
  unsigned short* Vt  = ws;                       // aliases xb: written after GEMM
  unsigned short* WqT = ws + 8388608;
  unsigned short* WkT = WqT + 1048576;
  unsigned short* WvT = WkT + 1048576;
  unsigned short* WoT = WvT + 1048576;
  unsigned short* QKV = WoT + 1048576;            // 8192*3072
  unsigned short* Ctx = QKV + 25165824;           // 8192*1024

  cvt_x<<<2048, 256, 0, stream>>>(x, xb, 8192 * 1024 / 4);

  dim3 tb(32, 8), tg(32, 32, 4);
  transpose_w4<<<tg, tb, 0, stream>>>(Wq, Wk, Wv, Wo, WqT);

  // fused QKV projection: M=8192, N=3072, K=1024 (256x192 tiles, 512 blocks = 2 rounds)
  gemm3b<3, 0><<<512, 512, 0, stream>>>(xb, WqT, QKV, nullptr, nullptr,
                                        8192, 3072, 1024);

  // V -> Vt[bh][hd][s_perm]  (xb dead; Vt aliases it)
  transpose_v<<<2048, 256, 0, stream>>>(QKV, Vt);

  // flash attention: 64 bh x 16 paired-strip blocks
  flash_attn<<<1024, 256, 0, stream>>>(QKV, Vt, Ctx);

  // output projection + bias: fp32 out (256x128 tiles, 256 blocks = 1 round)
  gemm3b<2, 1><<<256, 512, 0, stream>>>(Ctx, WoT, nullptr, out, bo,
                                        8192, 1024, 1024);
}

// Round 11
// 156.866 us; speedup vs baseline: 1.0157x; 1.0157x over previous
//
#include <hip/hip_runtime.h>

typedef __attribute__((ext_vector_type(8))) short bf16x8;
typedef __attribute__((ext_vector_type(4))) float f32x4;
typedef __attribute__((ext_vector_type(2))) float f32x2;
typedef __attribute__((ext_vector_type(4))) unsigned uint4v;

#define SM_C 0.18033688011112042f  // 0.125 * log2(e)
#define MFMA16 __builtin_amdgcn_mfma_f32_16x16x32_bf16

__device__ __forceinline__ unsigned short f2bf(float f) {
  unsigned u = __builtin_bit_cast(unsigned, f);
  u += 0x7fffu + ((u >> 16) & 1u);
  return (unsigned short)(u >> 16);
}

__device__ __forceinline__ unsigned cvtpk(float lo, float hi) {
  unsigned r;
  asm volatile("v_cvt_pk_bf16_f32 %0, %1, %2" : "=v"(r) : "v"(lo), "v"(hi));
  return r;
}

__device__ __forceinline__ f32x2 pk_fma(f32x2 a, f32x2 b, f32x2 c) {
  f32x2 d;
  asm("v_pk_fma_f32 %0, %1, %2, %3" : "=v"(d) : "v"(a), "v"(b), "v"(c));
  return d;
}
__device__ __forceinline__ f32x2 pk_add(f32x2 a, f32x2 b) {
  f32x2 d;
  asm("v_pk_add_f32 %0, %1, %2" : "=v"(d) : "v"(a), "v"(b));
  return d;
}
__device__ __forceinline__ f32x2 pk_mul(f32x2 a, f32x2 b) {
  f32x2 d;
  asm("v_pk_mul_f32 %0, %1, %2" : "=v"(d) : "v"(a), "v"(b));
  return d;
}

__device__ __forceinline__ void gload16(const void* g, void* lds) {
  __builtin_amdgcn_global_load_lds(
      (const __attribute__((address_space(1))) void*)g,
      (__attribute__((address_space(3))) void*)lds, 16, 0, 0);
}

#define BARRIER __builtin_amdgcn_s_barrier()
#define LGKM0 asm volatile("s_waitcnt lgkmcnt(0)" ::: "memory")

// ---------------- x -> bf16 ----------------
__global__ __launch_bounds__(256) void cvt_x(const float* __restrict__ in,
                                             unsigned short* __restrict__ out,
                                             int n4) {
  int i = blockIdx.x * 256 + threadIdx.x;
  int stride = gridDim.x * 256;
  for (; i < n4; i += stride) {
    float4 v = ((const float4*)in)[i];
    unsigned short o0 = f2bf(v.x), o1 = f2bf(v.y), o2 = f2bf(v.z), o3 = f2bf(v.w);
    unsigned long long packed = (unsigned long long)o0 | ((unsigned long long)o1 << 16) |
                                ((unsigned long long)o2 << 32) | ((unsigned long long)o3 << 48);
    ((unsigned long long*)out)[i] = packed;
  }
}

// ---------------- 4x W[K][N] f32 -> WT[N][K] bf16 (fused) ----------------
__global__ __launch_bounds__(256) void transpose_w4(const float* __restrict__ W0,
                                                    const float* __restrict__ W1,
                                                    const float* __restrict__ W2,
                                                    const float* __restrict__ W3,
                                                    unsigned short* __restrict__ WT) {
  __shared__ float tile[32][33];
  const int z = blockIdx.z;
  const float* W = (z == 0) ? W0 : (z == 1) ? W1 : (z == 2) ? W2 : W3;
  unsigned short* WTo = WT + (size_t)z * 1048576;
  int bx = blockIdx.x, by = blockIdx.y;
  int x = bx * 32 + threadIdx.x;
  for (int i = 0; i < 4; ++i) {
    int r = threadIdx.y + i * 8;
    tile[r][threadIdx.x] = W[(by * 32 + r) * 1024 + x];
  }
  __syncthreads();
  int nx = by * 32 + threadIdx.x;
  for (int i = 0; i < 4; ++i) {
    int r = threadIdx.y + i * 8;
    WTo[(long)(bx * 32 + r) * 1024 + nx] = f2bf(tile[threadIdx.x][r]);
  }
}

// ---------------- GEMM: A triple-buffer, B double-buffer, 1 vmcnt/K-tile ----
// MODE 0: QKV split-plane output (tn 0-7 -> Q plane, 8-15 -> K plane,
//         16-23 -> V^T scatter with key-permutation, packed 8B stores).
// MODE 1: f32 + bias output.
template <int NR, int MODE>
__global__ __launch_bounds__(512, 1) void gemm3b(const unsigned short* __restrict__ A,
                                                 const unsigned short* __restrict__ BT,
                                                 unsigned short* __restrict__ Cb,
                                                 float* __restrict__ Cf,
                                                 const float* __restrict__ bias,
                                                 int M, int N, int K) {
  constexpr int BN = NR * 64;
  __shared__ alignas(16) unsigned short As[3][256 * 64];
  __shared__ alignas(16) unsigned short Bs[2][BN * 64];

  const int nbn = N / BN;
  const int tmg = (M / 256) / 8;
  const int cc = blockIdx.x >> 3, xc = blockIdx.x & 7;
  const int tm = xc * tmg + cc / nbn, tn = cc % nbn;

  const int t = threadIdx.x, l = t & 63, wid = t >> 6;
  const int wm = wid >> 2, wn = wid & 3;
  const int lr = l & 15, lg = l >> 4;

  f32x4 acc[8][NR] = {};

  const int sq = t >> 3;
  const int sslot8 = ((t & 7) ^ (sq & 7)) * 8;
  const unsigned short* Ath = A + ((long)tm * 256 + sq) * K + sslot8;
  const unsigned short* Bth = BT + ((long)tn * BN + sq) * K + sslot8;
  const int ldsoff = sq * 64 + (t & 7) * 8;

#define STGA(buf, q, kt) \
  gload16(Ath + (long)((q)*64) * K + (kt)*64, &As[buf][(q)*4096 + ldsoff])
#define STGB(buf, u, kt) \
  gload16(Bth + (long)((u)*64) * K + (kt)*64, &Bs[buf][(u)*4096 + ldsoff])

  const int NT = K >> 6;
#pragma unroll
  for (int q = 0; q < 4; ++q) STGA(0, q, 0);
#pragma unroll
  for (int u = 0; u < NR; ++u) STGB(0, u, 0);
#pragma unroll
  for (int q = 0; q < 4; ++q) STGA(1, q, 1);

  const int offk0 = (lg ^ (lr & 7)) * 8;
  const int offk1 = ((4 + lg) ^ (lr & 7)) * 8;
  const int arow0 = (wm * 128 + lr) * 64;
  const int brow0 = (wn * (NR * 16) + lr) * 64;

#define DS_A(MH)                                                   \
  _Pragma("unroll") for (int m_ = 0; m_ < 4; ++m_) {               \
    const unsigned short* ap_ = Ac + arow0 + ((MH)*4 + m_) * 1024; \
    af[m_][0] = *(const bf16x8*)(ap_ + offk0);                     \
    af[m_][1] = *(const bf16x8*)(ap_ + offk1);                     \
  }
#define DS_B_ALL                                          \
  _Pragma("unroll") for (int n_ = 0; n_ < NR; ++n_) {     \
    const unsigned short* bp_ = Bc + brow0 + n_ * 1024;   \
    bfr[n_][0] = *(const bf16x8*)(bp_ + offk0);           \
    bfr[n_][1] = *(const bf16x8*)(bp_ + offk1);           \
  }
#define MM(MH)                                                              \
  __builtin_amdgcn_s_setprio(1);                                            \
  _Pragma("unroll") for (int m_ = 0; m_ < 4; ++m_)                          \
  _Pragma("unroll") for (int n_ = 0; n_ < NR; ++n_) {                       \
    acc[(MH)*4 + m_][n_] = MFMA16(af[m_][0], bfr[n_][0],                    \
                                  acc[(MH)*4 + m_][n_], 0, 0, 0);           \
    acc[(MH)*4 + m_][n_] = MFMA16(af[m_][1], bfr[n_][1],                    \
                                  acc[(MH)*4 + m_][n_], 0, 0, 0);           \
  }                                                                         \
  __builtin_amdgcn_s_setprio(0);

  int cur3 = 0;
  int stg3 = 2;
  for (int tt = 0; tt < NT; ++tt) {
    const unsigned short* Ac = As[cur3];
    const unsigned short* Bc = Bs[tt & 1];

    bf16x8 af[4][2];
    bf16x8 bfr[NR][2];

    if (tt == NT - 1) asm volatile("s_waitcnt vmcnt(0)" ::: "memory");
    else              asm volatile("s_waitcnt vmcnt(4)" ::: "memory");
    BARRIER;
    DS_A(0);
    DS_B_ALL;
    if (tt + 1 < NT) {
      const int nbB = (tt + 1) & 1;
#pragma unroll
      for (int u = 0; u < NR; ++u) STGB(nbB, u, tt + 1);
    }
    BARRIER;
    LGKM0;
    MM(0);

    DS_A(1);
    if (tt + 2 < NT) {
#pragma unroll
      for (int q = 0; q < 4; ++q) STGA(stg3, q, tt + 2);
    }
    BARRIER;
    LGKM0;
    MM(1);

    cur3 = (cur3 == 2) ? 0 : cur3 + 1;
    stg3 = (stg3 == 2) ? 0 : stg3 + 1;
  }
#undef DS_A
#undef DS_B_ALL
#undef MM
#undef STGA
#undef STGB

  const long crow = (long)tm * 256 + wm * 128;
  const int ccol = tn * BN + wn * (NR * 16);

  if constexpr (MODE == 1) {
#pragma unroll
    for (int m = 0; m < 8; ++m)
#pragma unroll
      for (int n = 0; n < NR; ++n)
#pragma unroll
        for (int r = 0; r < 4; ++r) {
          long row = crow + m * 16 + lg * 4 + r;
          int col = ccol + n * 16 + lr;
          Cf[row * N + col] = acc[m][n][r] + bias[col];
        }
  } else {
    if (tn < 16) {
      // Q plane (tn 0-7) or K plane (tn 8-15), stride 1024
      unsigned short* plane = Cb + ((tn < 8) ? 0 : 8388608);
      const int pc = ccol - ((tn < 8) ? 0 : 1024);
#pragma unroll
      for (int m = 0; m < 8; ++m)
#pragma unroll
        for (int n = 0; n < NR; ++n)
#pragma unroll
          for (int r = 0; r < 4; ++r) {
            long row = crow + m * 16 + lg * 4 + r;
            plane[row * 1024 + pc + n * 16 + lr] = f2bf(acc[m][n][r]);
          }
    } else {
      // V^T plane with key permutation: Vt[(b*16+h)*64+hd][2048 s-perm]
      unsigned short* VtW = Cb + 16777216;
      const int bq = (tm >> 3) << 4;                 // b*16
      const int sbase = (tm & 7) * 256 + wm * 128;   // crow & 2047
#pragma unroll
      for (int m = 0; m < 8; ++m) {
        const int lwb = (m * 16 + lg * 4) & 63;
        const int stt = (sbase + m * 16 + lg * 4) >> 6;
        const int vp0 = (lwb & 32) | (((lwb >> 2) & 3) << 3) | (((lwb >> 4) & 1) << 2);
#pragma unroll
        for (int n = 0; n < NR; ++n) {
          const int vcol = ccol + n * 16 + lr - 2048;
          const long vtrow = (long)(bq + (vcol >> 6)) * 64 + (vcol & 63);
          unsigned long long pk4 =
              (unsigned long long)f2bf(acc[m][n][0]) |
              ((unsigned long long)f2bf(acc[m][n][1]) << 16) |
              ((unsigned long long)f2bf(acc[m][n][2]) << 32) |
              ((unsigned long long)f2bf(acc[m][n][3]) << 48);
          *(unsigned long long*)(VtW + vtrow * 2048 + stt * 64 + vp0) = pk4;
        }
      }
    }
  }
}

// ---------------- Flash attention tile body ----------------
template <int TWO>
__device__ __forceinline__ void attn_tile(
    const unsigned short* __restrict__ Kc, const unsigned short* __restrict__ Vc,
    int lr, int lg, bool mask0, bool mask1, int kv0, int q0row, int q1row,
    const bf16x8 (&qf)[2][2], f32x4 (&cacc)[2][4], float (&m_r)[2], float (&l_r)[2]) {
  constexpr int S0 = TWO ? 0 : 1;
  f32x4 p[2][4];
#pragma unroll
  for (int s = S0; s < 2; ++s)
#pragma unroll
    for (int g = 0; g < 4; ++g) p[s][g] = f32x4{0.f, 0.f, 0.f, 0.f};

  __builtin_amdgcn_s_setprio(1);
#pragma unroll
  for (int g = 0; g < 4; ++g) {
    const int key = g * 16 + lr;
    const int swz = (key & 7) << 3;
#pragma unroll
    for (int c = 0; c < 2; ++c) {
      bf16x8 kf = *(const bf16x8*)(Kc + key * 64 + ((c * 32 + lg * 8) ^ swz));
#pragma unroll
      for (int s = S0; s < 2; ++s)
        p[s][g] = MFMA16(kf, qf[s][c], p[s][g], 0, 0, 0);
    }
  }
  __builtin_amdgcn_s_setprio(0);

  if (TWO && mask0) {
#pragma unroll
    for (int g = 0; g < 4; ++g)
#pragma unroll
      for (int r = 0; r < 4; ++r)
        if (kv0 + g * 16 + lg * 4 + r > q0row) p[0][g][r] = -1e30f;
  }
  if (mask1) {
#pragma unroll
    for (int g = 0; g < 4; ++g)
#pragma unroll
      for (int r = 0; r < 4; ++r)
        if (kv0 + g * 16 + lg * 4 + r > q1row) p[1][g][r] = -1e30f;
  }

  const f32x2 C2 = {SM_C, SM_C};
  unsigned pk[2][4][2];
#pragma unroll
  for (int s = S0; s < 2; ++s) {
    float mloc = p[s][0][0];
#pragma unroll
    for (int g = 0; g < 4; ++g)
#pragma unroll
      for (int r = 0; r < 4; ++r) mloc = fmaxf(mloc, p[s][g][r]);
    mloc = fmaxf(mloc, __shfl_xor(mloc, 16));
    mloc = fmaxf(mloc, __shfl_xor(mloc, 32));
    const bool defer = __all(mloc <= m_r[s] + 44.0f);
    const float mn = defer ? m_r[s] : fmaxf(m_r[s], mloc);
    f32x2 nmc2;
    nmc2[0] = nmc2[1] = -mn * SM_C;
    // exp args via packed fma, exp scalar (trans pipe)
    f32x2 ex[4][2];
#pragma unroll
    for (int g = 0; g < 4; ++g) {
      f32x2 lo = {p[s][g][0], p[s][g][1]};
      f32x2 hi = {p[s][g][2], p[s][g][3]};
      ex[g][0] = pk_fma(lo, C2, nmc2);
      ex[g][1] = pk_fma(hi, C2, nmc2);
      ex[g][0][0] = __builtin_amdgcn_exp2f(ex[g][0][0]);
      ex[g][0][1] = __builtin_amdgcn_exp2f(ex[g][0][1]);
      ex[g][1][0] = __builtin_amdgcn_exp2f(ex[g][1][0]);
      ex[g][1][1] = __builtin_amdgcn_exp2f(ex[g][1][1]);
    }
    // packed row-sum tree
    f32x2 r0 = pk_add(ex[0][0], ex[0][1]);
    f32x2 r1 = pk_add(ex[1][0], ex[1][1]);
    f32x2 r2 = pk_add(ex[2][0], ex[2][1]);
    f32x2 r3 = pk_add(ex[3][0], ex[3][1]);
    f32x2 r01 = pk_add(r0, r1);
    f32x2 r23 = pk_add(r2, r3);
    f32x2 rv = pk_add(r01, r23);
    float rs = rv[0] + rv[1];
    rs += __shfl_xor(rs, 16);
    rs += __shfl_xor(rs, 32);
    if (defer) {
      l_r[s] += rs;
    } else {
      float alpha = __builtin_amdgcn_exp2f((m_r[s] - mn) * SM_C);
      l_r[s] = l_r[s] * alpha + rs;
      m_r[s] = mn;
      float alq[4];
#pragma unroll
      for (int r = 0; r < 4; ++r) alq[r] = __shfl(alpha, lg * 20 + r);
      f32x2 alo = {alq[0], alq[1]};
      f32x2 ahi = {alq[2], alq[3]};
#pragma unroll
      for (int n = 0; n < 4; ++n) {
        f32x2 clo = {cacc[s][n][0], cacc[s][n][1]};
        f32x2 chi = {cacc[s][n][2], cacc[s][n][3]};
        clo = pk_mul(clo, alo);
        chi = pk_mul(chi, ahi);
        cacc[s][n][0] = clo[0]; cacc[s][n][1] = clo[1];
        cacc[s][n][2] = chi[0]; cacc[s][n][3] = chi[1];
      }
    }
#pragma unroll
    for (int g = 0; g < 4; ++g) {
      pk[s][g][0] = cvtpk(ex[g][0][0], ex[g][0][1]);
      pk[s][g][1] = cvtpk(ex[g][1][0], ex[g][1][1]);
    }
  }

#pragma unroll
  for (int sl = 0; sl < 2; ++sl) {
    bf16x8 vf[4];
#pragma unroll
    for (int n = 0; n < 4; ++n) {
      const int hd = n * 16 + lr;
      vf[n] = *(const bf16x8*)(Vc + hd * 64 + ((sl * 32 + lg * 8) ^ ((hd & 7) << 3)));
    }
    __builtin_amdgcn_s_setprio(1);
#pragma unroll
    for (int s = S0; s < 2; ++s) {
      uint4v pw = {pk[s][2 * sl][0], pk[s][2 * sl][1], pk[s][2 * sl + 1][0], pk[s][2 * sl + 1][1]};
      bf16x8 pa = __builtin_bit_cast(bf16x8, pw);
#pragma unroll
      for (int n = 0; n < 4; ++n)
        cacc[s][n] = MFMA16(pa, vf[n], cacc[s][n], 0, 0, 0);
    }
    __builtin_amdgcn_s_setprio(0);
  }
}

// ---------------- Flash attention (paired strips, counted-vmcnt pipeline) ---
// Q plane Qp[8192][1024], K plane Kp[8192][1024], Vt[64bh*64hd][2048 s-perm].
__global__ __launch_bounds__(256, 4) void flash_attn(const unsigned short* __restrict__ Qp,
                                                     const unsigned short* __restrict__ Kp,
                                                     const unsigned short* __restrict__ Vt,
                                                     unsigned short* __restrict__ Ctx) {
  __shared__ alignas(16) unsigned short Ks[2][64 * 64];
  __shared__ alignas(16) unsigned short Vs[2][64 * 64];
  const int bid = blockIdx.x;
  const int qt = bid >> 6;
  const int bh = bid & 63;
  const int b = bh >> 4, h = bh & 15;
  const int t = threadIdx.x, l = t & 63, w = t >> 6;
  const int lr = l & 15, lg = l >> 4;
  const long rowbase = (long)b * 2048;
  const int colbase = h * 64;
  const int q0 = qt * 64 + w * 16;
  const int q1 = (31 - qt) * 64 + w * 16;
  const int q0row = q0 + lr, q1row = q1 + lr;
  const int nkv = 32 - qt;

  bf16x8 qf[2][2];
#pragma unroll
  for (int c = 0; c < 2; ++c) {
    qf[0][c] = *(const bf16x8*)(Qp + (rowbase + q0 + lr) * 1024 + colbase + c * 32 + lg * 8);
    qf[1][c] = *(const bf16x8*)(Qp + (rowbase + q1 + lr) * 1024 + colbase + c * 32 + lg * 8);
  }

  f32x4 cacc[2][4];
  float m_r[2], l_r[2];
#pragma unroll
  for (int s = 0; s < 2; ++s) {
    m_r[s] = -1e30f;
    l_r[s] = 0.f;
#pragma unroll
    for (int n = 0; n < 4; ++n) cacc[s][n] = f32x4{0.f, 0.f, 0.f, 0.f};
  }

  const int srow = w * 16 + (l >> 3);
  const int scol = (l & 7) * 8;
  const int kswz = scol ^ ((srow & 7) << 3);
  const unsigned short* kp = Kp + (rowbase + srow) * 1024 + colbase + kswz;
  const unsigned short* vp = Vt + ((long)(bh * 64 + srow)) * 2048 + kswz;
  unsigned short* ksd0 = &Ks[0][(w * 16) * 64];
  unsigned short* vsd0 = &Vs[0][(w * 16) * 64];

#define STAGE(buf)                                    \
  do {                                                \
    gload16(kp, ksd0 + (buf) * 4096);                 \
    gload16(kp + 8 * 1024, ksd0 + (buf) * 4096 + 512);\
    gload16(vp, vsd0 + (buf) * 4096);                 \
    gload16(vp + 8 * 2048, vsd0 + (buf) * 4096 + 512);\
    kp += 64 * 1024;                                  \
    vp += 64;                                         \
  } while (0)

#define TILE_WAIT(j)                                                          \
  do {                                                                        \
    if ((j) == nkv - 1) asm volatile("s_waitcnt vmcnt(0)" ::: "memory");      \
    else                asm volatile("s_waitcnt vmcnt(4)" ::: "memory");      \
    asm volatile("s_barrier" ::: "memory");                                   \
  } while (0)

  STAGE(0);
  STAGE(1);

  int j = 0;
  for (; j <= qt; ++j) {  // both strips active
    const int cur = j & 1;
    TILE_WAIT(j);
    attn_tile<1>(Ks[cur], Vs[cur], lr, lg, j == qt, false, j * 64, q0row, q1row,
                 qf, cacc, m_r, l_r);
    asm volatile("s_barrier" ::: "memory");
    if (j + 2 < nkv) STAGE(cur);
  }
  for (; j < nkv; ++j) {  // long strip only
    const int cur = j & 1;
    TILE_WAIT(j);
    attn_tile<0>(Ks[cur], Vs[cur], lr, lg, false, j == nkv - 1, j * 64, q0row, q1row,
                 qf, cacc, m_r, l_r);
    asm volatile("s_barrier" ::: "memory");
    if (j + 2 < nkv) STAGE(cur);
  }
#undef STAGE
#undef TILE_WAIT

#pragma unroll
  for (int s = 0; s < 2; ++s) {
    float invl = 1.f / l_r[s];
    float ilq[4];
#pragma unroll
    for (int r = 0; r < 4; ++r) ilq[r] = __shfl(invl, lg * 20 + r);
    const int qs = (s == 0) ? q0 : q1;
#pragma unroll
    for (int n = 0; n < 4; ++n)
#pragma unroll
      for (int r = 0; r < 4; ++r) {
        long row = rowbase + qs + lg * 4 + r;
        Ctx[row * 1024 + colbase + n * 16 + lr] = f2bf(cacc[s][n][r] * ilq[r]);
      }
  }
}

extern "C" void kernel_launch(void* const* d_in, const int* in_sizes, int n_in,
                              void* d_out, int out_size, void* d_ws, size_t ws_size,
                              hipStream_t stream) {
  (void)in_sizes; (void)n_in; (void)out_size; (void)ws_size;
  const float* x  = (const float*)d_in[0];
  const float* Wq = (const float*)d_in[1];
  const float* Wk = (const float*)d_in[2];
  const float* Wv = (const float*)d_in[3];
  const float* Wo = (const float*)d_in[4];
  const float* bo = (const float*)d_in[5];
  float* out = (float*)d_out;

  unsigned short* ws = (unsigned short*)d_ws;
  unsigned short* xb  = ws;                       // 8192*1024 bf16
  unsigned short* WqT = ws + 8388608;             // 4x 1024*1024 (Wq,Wk,Wv,Wo)
  unsigned short* WoT = WqT + 3145728;
  unsigned short* QKV = WqT + 4194304;            // 3 planes: Q | K | V^T (8M each)
  unsigned short* Qp  = QKV;
  unsigned short* Kp  = QKV + 8388608;
  unsigned short* Vt  = QKV + 16777216;
  unsigned short* Ctx = QKV + 25165824;           // 8192*1024

  cvt_x<<<2048, 256, 0, stream>>>(x, xb, 8192 * 1024 / 4);

  dim3 tb(32, 8), tg(32, 32, 4);
  transpose_w4<<<tg, tb, 0, stream>>>(Wq, Wk, Wv, Wo, WqT);

  // fused QKV projection: M=8192, N=3072, K=1024 (256x128 tiles, 768 blocks =
  // 3 exact rounds); V columns written transposed+permuted straight to Vt.
  gemm3b<2, 0><<<768, 512, 0, stream>>>(xb, WqT, QKV, nullptr, nullptr,
                                        8192, 3072, 1024);

  // flash attention: 64 bh x 16 paired-strip blocks
  flash_attn<<<1024, 256, 0, stream>>>(Qp, Kp, Vt, Ctx);

  // output projection + bias: fp32 out (256x128 tiles, 256 blocks = 1 round)
  gemm3b<2, 1><<<256, 512, 0, stream>>>(Ctx, WoT, nullptr, out, bo,
                                        8192, 1024, 1024);
}

// Round 12
// 151.290 us; speedup vs baseline: 1.0531x; 1.0369x over previous
//
#include <hip/hip_runtime.h>

typedef __attribute__((ext_vector_type(8))) short bf16x8;
typedef __attribute__((ext_vector_type(4))) float f32x4;
typedef __attribute__((ext_vector_type(2))) float f32x2;
typedef __attribute__((ext_vector_type(4))) unsigned uint4v;

#define SM_C 0.18033688011112042f  // 0.125 * log2(e)
#define MFMA16 __builtin_amdgcn_mfma_f32_16x16x32_bf16

__device__ __forceinline__ unsigned short f2bf(float f) {
  unsigned u = __builtin_bit_cast(unsigned, f);
  u += 0x7fffu + ((u >> 16) & 1u);
  return (unsigned short)(u >> 16);
}

__device__ __forceinline__ unsigned cvtpk(float lo, float hi) {
  unsigned r;
  asm volatile("v_cvt_pk_bf16_f32 %0, %1, %2" : "=v"(r) : "v"(lo), "v"(hi));
  return r;
}

__device__ __forceinline__ f32x2 pk_fma(f32x2 a, f32x2 b, f32x2 c) {
  f32x2 d;
  asm("v_pk_fma_f32 %0, %1, %2, %3" : "=v"(d) : "v"(a), "v"(b), "v"(c));
  return d;
}
__device__ __forceinline__ f32x2 pk_add(f32x2 a, f32x2 b) {
  f32x2 d;
  asm("v_pk_add_f32 %0, %1, %2" : "=v"(d) : "v"(a), "v"(b));
  return d;
}
__device__ __forceinline__ f32x2 pk_mul(f32x2 a, f32x2 b) {
  f32x2 d;
  asm("v_pk_mul_f32 %0, %1, %2" : "=v"(d) : "v"(a), "v"(b));
  return d;
}

__device__ __forceinline__ void gload16(const void* g, void* lds) {
  __builtin_amdgcn_global_load_lds(
      (const __attribute__((address_space(1))) void*)g,
      (__attribute__((address_space(3))) void*)lds, 16, 0, 0);
}

#define BARRIER __builtin_amdgcn_s_barrier()
#define LGKM0 asm volatile("s_waitcnt lgkmcnt(0)" ::: "memory")

// ---------------- x -> bf16 ----------------
__global__ __launch_bounds__(256) void cvt_x(const float* __restrict__ in,
                                             unsigned short* __restrict__ out,
                                             int n4) {
  int i = blockIdx.x * 256 + threadIdx.x;
  int stride = gridDim.x * 256;
  for (; i < n4; i += stride) {
    float4 v = ((const float4*)in)[i];
    unsigned short o0 = f2bf(v.x), o1 = f2bf(v.y), o2 = f2bf(v.z), o3 = f2bf(v.w);
    unsigned long long packed = (unsigned long long)o0 | ((unsigned long long)o1 << 16) |
                                ((unsigned long long)o2 << 32) | ((unsigned long long)o3 << 48);
    ((unsigned long long*)out)[i] = packed;
  }
}

// ---------------- 4x W[K][N] f32 -> WT[N][K] bf16 (fused) ----------------
__global__ __launch_bounds__(256) void transpose_w4(const float* __restrict__ W0,
                                                    const float* __restrict__ W1,
                                                    const float* __restrict__ W2,
                                                    const float* __restrict__ W3,
                                                    unsigned short* __restrict__ WT) {
  __shared__ float tile[32][33];
  const int z = blockIdx.z;
  const float* W = (z == 0) ? W0 : (z == 1) ? W1 : (z == 2) ? W2 : W3;
  unsigned short* WTo = WT + (size_t)z * 1048576;
  int bx = blockIdx.x, by = blockIdx.y;
  int x = bx * 32 + threadIdx.x;
  for (int i = 0; i < 4; ++i) {
    int r = threadIdx.y + i * 8;
    tile[r][threadIdx.x] = W[(by * 32 + r) * 1024 + x];
  }
  __syncthreads();
  int nx = by * 32 + threadIdx.x;
  for (int i = 0; i < 4; ++i) {
    int r = threadIdx.y + i * 8;
    WTo[(long)(bx * 32 + r) * 1024 + nx] = f2bf(tile[threadIdx.x][r]);
  }
}

// ---------------- GEMM: A triple-buffer, B double-buffer, 1 vmcnt/K-tile ----
// MODE 0: split-plane output routed per 16-col group (Q plane / K plane /
//         V^T key-permuted packed-8B scatter).  MODE 1: f32 + bias.
template <int NR, int MODE>
__global__ __launch_bounds__(512, 1) void gemm3b(const unsigned short* __restrict__ A,
                                                 const unsigned short* __restrict__ BT,
                                                 unsigned short* __restrict__ Cb,
                                                 float* __restrict__ Cf,
                                                 const float* __restrict__ bias,
                                                 int M, int N, int K) {
  constexpr int BN = NR * 64;
  __shared__ alignas(16) unsigned short As[3][256 * 64];
  __shared__ alignas(16) unsigned short Bs[2][BN * 64];

  const int nbn = N / BN;
  const int tmg = (M / 256) / 8;
  const int cc = blockIdx.x >> 3, xc = blockIdx.x & 7;
  const int tm = xc * tmg + cc / nbn, tn = cc % nbn;

  const int t = threadIdx.x, l = t & 63, wid = t >> 6;
  const int wm = wid >> 2, wn = wid & 3;
  const int lr = l & 15, lg = l >> 4;

  f32x4 acc[8][NR] = {};

  const int sq = t >> 3;
  const int sslot8 = ((t & 7) ^ (sq & 7)) * 8;
  const unsigned short* Ath = A + ((long)tm * 256 + sq) * K + sslot8;
  const unsigned short* Bth = BT + ((long)tn * BN + sq) * K + sslot8;
  const int ldsoff = sq * 64 + (t & 7) * 8;

#define STGA(buf, q, kt) \
  gload16(Ath + (long)((q)*64) * K + (kt)*64, &As[buf][(q)*4096 + ldsoff])
#define STGB(buf, u, kt) \
  gload16(Bth + (long)((u)*64) * K + (kt)*64, &Bs[buf][(u)*4096 + ldsoff])

  const int NT = K >> 6;
#pragma unroll
  for (int q = 0; q < 4; ++q) STGA(0, q, 0);
#pragma unroll
  for (int u = 0; u < NR; ++u) STGB(0, u, 0);
#pragma unroll
  for (int q = 0; q < 4; ++q) STGA(1, q, 1);

  const int offk0 = (lg ^ (lr & 7)) * 8;
  const int offk1 = ((4 + lg) ^ (lr & 7)) * 8;
  const int arow0 = (wm * 128 + lr) * 64;
  const int brow0 = (wn * (NR * 16) + lr) * 64;

#define DS_A(MH)                                                   \
  _Pragma("unroll") for (int m_ = 0; m_ < 4; ++m_) {               \
    const unsigned short* ap_ = Ac + arow0 + ((MH)*4 + m_) * 1024; \
    af[m_][0] = *(const bf16x8*)(ap_ + offk0);                     \
    af[m_][1] = *(const bf16x8*)(ap_ + offk1);                     \
  }
#define DS_B_ALL                                          \
  _Pragma("unroll") for (int n_ = 0; n_ < NR; ++n_) {     \
    const unsigned short* bp_ = Bc + brow0 + n_ * 1024;   \
    bfr[n_][0] = *(const bf16x8*)(bp_ + offk0);           \
    bfr[n_][1] = *(const bf16x8*)(bp_ + offk1);           \
  }
#define MM(MH)                                                              \
  __builtin_amdgcn_s_setprio(1);                                            \
  _Pragma("unroll") for (int m_ = 0; m_ < 4; ++m_)                          \
  _Pragma("unroll") for (int n_ = 0; n_ < NR; ++n_) {                       \
    acc[(MH)*4 + m_][n_] = MFMA16(af[m_][0], bfr[n_][0],                    \
                                  acc[(MH)*4 + m_][n_], 0, 0, 0);           \
    acc[(MH)*4 + m_][n_] = MFMA16(af[m_][1], bfr[n_][1],                    \
                                  acc[(MH)*4 + m_][n_], 0, 0, 0);           \
  }                                                                         \
  __builtin_amdgcn_s_setprio(0);

  int cur3 = 0;
  int stg3 = 2;
  for (int tt = 0; tt < NT; ++tt) {
    const unsigned short* Ac = As[cur3];
    const unsigned short* Bc = Bs[tt & 1];

    bf16x8 af[4][2];
    bf16x8 bfr[NR][2];

    if (tt == NT - 1) asm volatile("s_waitcnt vmcnt(0)" ::: "memory");
    else              asm volatile("s_waitcnt vmcnt(4)" ::: "memory");
    BARRIER;
    DS_A(0);
    DS_B_ALL;
    if (tt + 1 < NT) {
      const int nbB = (tt + 1) & 1;
#pragma unroll
      for (int u = 0; u < NR; ++u) STGB(nbB, u, tt + 1);
    }
    BARRIER;
    LGKM0;
    MM(0);

    DS_A(1);
    if (tt + 2 < NT) {
#pragma unroll
      for (int q = 0; q < 4; ++q) STGA(stg3, q, tt + 2);
    }
    BARRIER;
    LGKM0;
    MM(1);

    cur3 = (cur3 == 2) ? 0 : cur3 + 1;
    stg3 = (stg3 == 2) ? 0 : stg3 + 1;
  }
#undef DS_A
#undef DS_B_ALL
#undef MM
#undef STGA
#undef STGB

  const long crow = (long)tm * 256 + wm * 128;
  const int ccol = tn * BN + wn * (NR * 16);

  if constexpr (MODE == 1) {
#pragma unroll
    for (int m = 0; m < 8; ++m)
#pragma unroll
      for (int n = 0; n < NR; ++n)
#pragma unroll
        for (int r = 0; r < 4; ++r) {
          long row = crow + m * 16 + lg * 4 + r;
          int col = ccol + n * 16 + lr;
          Cf[row * N + col] = acc[m][n][r] + bias[col];
        }
  } else {
    // per-16-col-group plane routing (1024 % 16 == 0 -> group in one plane)
#pragma unroll
    for (int n = 0; n < NR; ++n) {
      const int colg = ccol + n * 16;  // wave-uniform
      const int plane = colg >> 10;
      if (plane < 2) {
        unsigned short* pl = Cb + (size_t)plane * 8388608;
        const int pc = (colg & 1023) + lr;
#pragma unroll
        for (int m = 0; m < 8; ++m)
#pragma unroll
          for (int r = 0; r < 4; ++r) {
            long row = crow + m * 16 + lg * 4 + r;
            pl[row * 1024 + pc] = f2bf(acc[m][n][r]);
          }
      } else {
        // V^T plane, key permutation: Vt[(b*16+h)*64+hd][2048 s-perm]
        unsigned short* VtW = Cb + 16777216;
        const int bq = (tm >> 3) << 4;
        const int sbase = ((tm & 7) << 8) + wm * 128;
        const int vcol = (colg & 1023) + lr;
        const long vtrow = (long)(bq + (vcol >> 6)) * 64 + (vcol & 63);
#pragma unroll
        for (int m = 0; m < 8; ++m) {
          const int srow_ = sbase + m * 16 + lg * 4;
          const int lwb = srow_ & 63;
          const int stt = srow_ >> 6;
          const int vp0 = (lwb & 32) | (((lwb >> 2) & 3) << 3) | (((lwb >> 4) & 1) << 2);
          unsigned long long pk4 =
              (unsigned long long)f2bf(acc[m][n][0]) |
              ((unsigned long long)f2bf(acc[m][n][1]) << 16) |
              ((unsigned long long)f2bf(acc[m][n][2]) << 32) |
              ((unsigned long long)f2bf(acc[m][n][3]) << 48);
          *(unsigned long long*)(VtW + vtrow * 2048 + stt * 64 + vp0) = pk4;
        }
      }
    }
  }
}

// ---------------- Flash attention tile body ----------------
template <int TWO>
__device__ __forceinline__ void attn_tile(
    const unsigned short* __restrict__ Kc, const unsigned short* __restrict__ Vc,
    int lr, int lg, bool mask0, bool mask1, int kv0, int q0row, int q1row,
    const bf16x8 (&qf)[2][2], f32x4 (&cacc)[2][4], float (&m_r)[2], float (&l_r)[2]) {
  constexpr int S0 = TWO ? 0 : 1;
  f32x4 p[2][4];
#pragma unroll
  for (int s = S0; s < 2; ++s)
#pragma unroll
    for (int g = 0; g < 4; ++g) p[s][g] = f32x4{0.f, 0.f, 0.f, 0.f};

  __builtin_amdgcn_s_setprio(1);
#pragma unroll
  for (int g = 0; g < 4; ++g) {
    const int key = g * 16 + lr;
    const int swz = (key & 7) << 3;
#pragma unroll
    for (int c = 0; c < 2; ++c) {
      bf16x8 kf = *(const bf16x8*)(Kc + key * 64 + ((c * 32 + lg * 8) ^ swz));
#pragma unroll
      for (int s = S0; s < 2; ++s)
        p[s][g] = MFMA16(kf, qf[s][c], p[s][g], 0, 0, 0);
    }
  }
  __builtin_amdgcn_s_setprio(0);

  if (TWO && mask0) {
#pragma unroll
    for (int g = 0; g < 4; ++g)
#pragma unroll
      for (int r = 0; r < 4; ++r)
        if (kv0 + g * 16 + lg * 4 + r > q0row) p[0][g][r] = -1e30f;
  }
  if (mask1) {
#pragma unroll
    for (int g = 0; g < 4; ++g)
#pragma unroll
      for (int r = 0; r < 4; ++r)
        if (kv0 + g * 16 + lg * 4 + r > q1row) p[1][g][r] = -1e30f;
  }

  const f32x2 C2 = {SM_C, SM_C};
  unsigned pk[2][4][2];
#pragma unroll
  for (int s = S0; s < 2; ++s) {
    // balanced max tree (depth 4) instead of linear 15-op chain
    f32x4 t0, t1;
#pragma unroll
    for (int r = 0; r < 4; ++r) {
      t0[r] = fmaxf(p[s][0][r], p[s][1][r]);
      t1[r] = fmaxf(p[s][2][r], p[s][3][r]);
    }
#pragma unroll
    for (int r = 0; r < 4; ++r) t0[r] = fmaxf(t0[r], t1[r]);
    float mloc = fmaxf(fmaxf(t0[0], t0[1]), fmaxf(t0[2], t0[3]));
    mloc = fmaxf(mloc, __shfl_xor(mloc, 16));
    mloc = fmaxf(mloc, __shfl_xor(mloc, 32));
    const bool defer = __all(mloc <= m_r[s] + 44.0f);
    const float mn = defer ? m_r[s] : fmaxf(m_r[s], mloc);
    f32x2 nmc2;
    nmc2[0] = nmc2[1] = -mn * SM_C;
    f32x2 ex[4][2];
#pragma unroll
    for (int g = 0; g < 4; ++g) {
      f32x2 lo = {p[s][g][0], p[s][g][1]};
      f32x2 hi = {p[s][g][2], p[s][g][3]};
      ex[g][0] = pk_fma(lo, C2, nmc2);
      ex[g][1] = pk_fma(hi, C2, nmc2);
      ex[g][0][0] = __builtin_amdgcn_exp2f(ex[g][0][0]);
      ex[g][0][1] = __builtin_amdgcn_exp2f(ex[g][0][1]);
      ex[g][1][0] = __builtin_amdgcn_exp2f(ex[g][1][0]);
      ex[g][1][1] = __builtin_amdgcn_exp2f(ex[g][1][1]);
    }
    f32x2 r0 = pk_add(ex[0][0], ex[0][1]);
    f32x2 r1 = pk_add(ex[1][0], ex[1][1]);
    f32x2 r2 = pk_add(ex[2][0], ex[2][1]);
    f32x2 r3 = pk_add(ex[3][0], ex[3][1]);
    f32x2 r01 = pk_add(r0, r1);
    f32x2 r23 = pk_add(r2, r3);
    f32x2 rv = pk_add(r01, r23);
    float rs = rv[0] + rv[1];
    rs += __shfl_xor(rs, 16);
    rs += __shfl_xor(rs, 32);
    if (defer) {
      l_r[s] += rs;
    } else {
      float alpha = __builtin_amdgcn_exp2f((m_r[s] - mn) * SM_C);
      l_r[s] = l_r[s] * alpha + rs;
      m_r[s] = mn;
      float alq[4];
#pragma unroll
      for (int r = 0; r < 4; ++r) alq[r] = __shfl(alpha, lg * 20 + r);
      f32x2 alo = {alq[0], alq[1]};
      f32x2 ahi = {alq[2], alq[3]};
#pragma unroll
      for (int n = 0; n < 4; ++n) {
        f32x2 clo = {cacc[s][n][0], cacc[s][n][1]};
        f32x2 chi = {cacc[s][n][2], cacc[s][n][3]};
        clo = pk_mul(clo, alo);
        chi = pk_mul(chi, ahi);
        cacc[s][n][0] = clo[0]; cacc[s][n][1] = clo[1];
        cacc[s][n][2] = chi[0]; cacc[s][n][3] = chi[1];
      }
    }
#pragma unroll
    for (int g = 0; g < 4; ++g) {
      pk[s][g][0] = cvtpk(ex[g][0][0], ex[g][0][1]);
      pk[s][g][1] = cvtpk(ex[g][1][0], ex[g][1][1]);
    }
  }

#pragma unroll
  for (int sl = 0; sl < 2; ++sl) {
    bf16x8 vf[4];
#pragma unroll
    for (int n = 0; n < 4; ++n) {
      const int hd = n * 16 + lr;
      vf[n] = *(const bf16x8*)(Vc + hd * 64 + ((sl * 32 + lg * 8) ^ ((hd & 7) << 3)));
    }
    __builtin_amdgcn_s_setprio(1);
#pragma unroll
    for (int s = S0; s < 2; ++s) {
      uint4v pw = {pk[s][2 * sl][0], pk[s][2 * sl][1], pk[s][2 * sl + 1][0], pk[s][2 * sl + 1][1]};
      bf16x8 pa = __builtin_bit_cast(bf16x8, pw);
#pragma unroll
      for (int n = 0; n < 4; ++n)
        cacc[s][n] = MFMA16(pa, vf[n], cacc[s][n], 0, 0, 0);
    }
    __builtin_amdgcn_s_setprio(0);
  }
}

// ---------------- Flash attention (paired strips, counted-vmcnt pipeline) ---
__global__ __launch_bounds__(256, 4) void flash_attn(const unsigned short* __restrict__ Qp,
                                                     const unsigned short* __restrict__ Kp,
                                                     const unsigned short* __restrict__ Vt,
                                                     unsigned short* __restrict__ Ctx) {
  __shared__ alignas(16) unsigned short Ks[2][64 * 64];
  __shared__ alignas(16) unsigned short Vs[2][64 * 64];
  const int bid = blockIdx.x;
  const int qt = bid >> 6;
  const int bh = bid & 63;
  const int b = bh >> 4, h = bh & 15;
  const int t = threadIdx.x, l = t & 63, w = t >> 6;
  const int lr = l & 15, lg = l >> 4;
  const long rowbase = (long)b * 2048;
  const int colbase = h * 64;
  const int q0 = qt * 64 + w * 16;
  const int q1 = (31 - qt) * 64 + w * 16;
  const int q0row = q0 + lr, q1row = q1 + lr;
  const int nkv = 32 - qt;

  bf16x8 qf[2][2];
#pragma unroll
  for (int c = 0; c < 2; ++c) {
    qf[0][c] = *(const bf16x8*)(Qp + (rowbase + q0 + lr) * 1024 + colbase + c * 32 + lg * 8);
    qf[1][c] = *(const bf16x8*)(Qp + (rowbase + q1 + lr) * 1024 + colbase + c * 32 + lg * 8);
  }

  f32x4 cacc[2][4];
  float m_r[2], l_r[2];
#pragma unroll
  for (int s = 0; s < 2; ++s) {
    m_r[s] = -1e30f;
    l_r[s] = 0.f;
#pragma unroll
    for (int n = 0; n < 4; ++n) cacc[s][n] = f32x4{0.f, 0.f, 0.f, 0.f};
  }

  const int srow = w * 16 + (l >> 3);
  const int scol = (l & 7) * 8;
  const int kswz = scol ^ ((srow & 7) << 3);
  const unsigned short* kp = Kp + (rowbase + srow) * 1024 + colbase + kswz;
  const unsigned short* vp = Vt + ((long)(bh * 64 + srow)) * 2048 + kswz;
  unsigned short* ksd0 = &Ks[0][(w * 16) * 64];
  unsigned short* vsd0 = &Vs[0][(w * 16) * 64];

#define STAGE(buf)                                    \
  do {                                                \
    gload16(kp, ksd0 + (buf) * 4096);                 \
    gload16(kp + 8 * 1024, ksd0 + (buf) * 4096 + 512);\
    gload16(vp, vsd0 + (buf) * 4096);                 \
    gload16(vp + 8 * 2048, vsd0 + (buf) * 4096 + 512);\
    kp += 64 * 1024;                                  \
    vp += 64;                                         \
  } while (0)

#define TILE_WAIT(j)                                                          \
  do {                                                                        \
    if ((j) == nkv - 1) asm volatile("s_waitcnt vmcnt(0)" ::: "memory");      \
    else                asm volatile("s_waitcnt vmcnt(4)" ::: "memory");      \
    asm volatile("s_barrier" ::: "memory");                                   \
  } while (0)

  STAGE(0);
  STAGE(1);

  int j = 0;
  for (; j <= qt; ++j) {  // both strips active
    const int cur = j & 1;
    TILE_WAIT(j);
    attn_tile<1>(Ks[cur], Vs[cur], lr, lg, j == qt, false, j * 64, q0row, q1row,
                 qf, cacc, m_r, l_r);
    asm volatile("s_barrier" ::: "memory");
    if (j + 2 < nkv) STAGE(cur);
  }
  for (; j < nkv; ++j) {  // long strip only
    const int cur = j & 1;
    TILE_WAIT(j);
    attn_tile<0>(Ks[cur], Vs[cur], lr, lg, false, j == nkv - 1, j * 64, q0row, q1row,
                 qf, cacc, m_r, l_r);
    asm volatile("s_barrier" ::: "memory");
    if (j + 2 < nkv) STAGE(cur);
  }
#undef STAGE
#undef TILE_WAIT

#pragma unroll
  for (int s = 0; s < 2; ++s) {
    float invl = 1.f / l_r[s];
    float ilq[4];
#pragma unroll
    for (int r = 0; r < 4; ++r) ilq[r] = __shfl(invl, lg * 20 + r);
    const int qs = (s == 0) ? q0 : q1;
#pragma unroll
    for (int n = 0; n < 4; ++n)
#pragma unroll
      for (int r = 0; r < 4; ++r) {
        long row = rowbase + qs + lg * 4 + r;
        Ctx[row * 1024 + colbase + n * 16 + lr] = f2bf(cacc[s][n][r] * ilq[r]);
      }
  }
}

extern "C" void kernel_launch(void* const* d_in, const int* in_sizes, int n_in,
                              void* d_out, int out_size, void* d_ws, size_t ws_size,
                              hipStream_t stream) {
  (void)in_sizes; (void)n_in; (void)out_size; (void)ws_size;
  const float* x  = (const float*)d_in[0];
  const float* Wq = (const float*)d_in[1];
  const float* Wk = (const float*)d_in[2];
  const float* Wv = (const float*)d_in[3];
  const float* Wo = (const float*)d_in[4];
  const float* bo = (const float*)d_in[5];
  float* out = (float*)d_out;

  unsigned short* ws = (unsigned short*)d_ws;
  unsigned short* xb  = ws;                       // 8192*1024 bf16
  unsigned short* WqT = ws + 8388608;             // 4x 1024*1024 (Wq,Wk,Wv,Wo)
  unsigned short* WoT = WqT + 3145728;
  unsigned short* QKV = WqT + 4194304;            // 3 planes: Q | K | V^T (8M each)
  unsigned short* Qp  = QKV;
  unsigned short* Kp  = QKV + 8388608;
  unsigned short* Vt  = QKV + 16777216;
  unsigned short* Ctx = QKV + 25165824;           // 8192*1024

  cvt_x<<<2048, 256, 0, stream>>>(x, xb, 8192 * 1024 / 4);

  dim3 tb(32, 8), tg(32, 32, 4);
  transpose_w4<<<tg, tb, 0, stream>>>(Wq, Wk, Wv, Wo, WqT);

  // fused QKV projection: M=8192, N=3072, K=1024 (256x192 tiles, 512 blocks =
  // 2 exact rounds); outputs routed to Q / K / V^T planes in the epilogue.
  gemm3b<3, 0><<<512, 512, 0, stream>>>(xb, WqT, QKV, nullptr, nullptr,
                                        8192, 3072, 1024);

  // flash attention: 64 bh x 16 paired-strip blocks
  flash_attn<<<1024, 256, 0, stream>>>(Qp, Kp, Vt, Ctx);

  // output projection + bias: fp32 out (256x128 tiles, 256 blocks = 1 round)
  gemm3b<2, 1><<<256, 512, 0, stream>>>(Ctx, WoT, nullptr, out, bo,
                                        8192, 1024, 1024);
}

// Round 14
// 138.642 us; speedup vs baseline: 1.1492x; 1.0912x over previous
//
#include <hip/hip_runtime.h>

typedef __attribute__((ext_vector_type(8))) short bf16x8;
typedef __attribute__((ext_vector_type(4))) float f32x4;
typedef __attribute__((ext_vector_type(4))) unsigned uint4v;

#define SM_C 0.18033688011112042f  // 0.125 * log2(e)
#define SM_M 20.0f                 // static softmax shift (exact; f32 overflow needs s>730)
#define MFMA16 __builtin_amdgcn_mfma_f32_16x16x32_bf16

__device__ __forceinline__ unsigned short f2bf(float f) {
  unsigned u = __builtin_bit_cast(unsigned, f);
  u += 0x7fffu + ((u >> 16) & 1u);
  return (unsigned short)(u >> 16);
}

__device__ __forceinline__ unsigned cvtpk(float lo, float hi) {
  unsigned r;
  asm volatile("v_cvt_pk_bf16_f32 %0, %1, %2" : "=v"(r) : "v"(lo), "v"(hi));
  return r;
}

__device__ __forceinline__ void gload16(const void* g, void* lds) {
  __builtin_amdgcn_global_load_lds(
      (const __attribute__((address_space(1))) void*)g,
      (__attribute__((address_space(3))) void*)lds, 16, 0, 0);
}

#define BARRIER __builtin_amdgcn_s_barrier()
#define LGKM0 asm volatile("s_waitcnt lgkmcnt(0)" ::: "memory")

// ---------------- x -> bf16 ----------------
__global__ __launch_bounds__(256) void cvt_x(const float* __restrict__ in,
                                             unsigned short* __restrict__ out,
                                             int n4) {
  int i = blockIdx.x * 256 + threadIdx.x;
  int stride = gridDim.x * 256;
  for (; i < n4; i += stride) {
    float4 v = ((const float4*)in)[i];
    unsigned short o0 = f2bf(v.x), o1 = f2bf(v.y), o2 = f2bf(v.z), o3 = f2bf(v.w);
    unsigned long long packed = (unsigned long long)o0 | ((unsigned long long)o1 << 16) |
                                ((unsigned long long)o2 << 32) | ((unsigned long long)o3 << 48);
    ((unsigned long long*)out)[i] = packed;
  }
}

// ---------------- 4x W[K][N] f32 -> WT[N][K] bf16 (fused) ----------------
__global__ __launch_bounds__(256) void transpose_w4(const float* __restrict__ W0,
                                                    const float* __restrict__ W1,
                                                    const float* __restrict__ W2,
                                                    const float* __restrict__ W3,
                                                    unsigned short* __restrict__ WT) {
  __shared__ float tile[32][33];
  const int z = blockIdx.z;
  const float* W = (z == 0) ? W0 : (z == 1) ? W1 : (z == 2) ? W2 : W3;
  unsigned short* WTo = WT + (size_t)z * 1048576;
  int bx = blockIdx.x, by = blockIdx.y;
  int x = bx * 32 + threadIdx.x;
  for (int i = 0; i < 4; ++i) {
    int r = threadIdx.y + i * 8;
    tile[r][threadIdx.x] = W[(by * 32 + r) * 1024 + x];
  }
  __syncthreads();
  int nx = by * 32 + threadIdx.x;
  for (int i = 0; i < 4; ++i) {
    int r = threadIdx.y + i * 8;
    WTo[(long)(bx * 32 + r) * 1024 + nx] = f2bf(tile[threadIdx.x][r]);
  }
}

// ---------------- GEMM: A triple-buffer, B double-buffer, 1 vmcnt/K-tile ----
// MODE 0: split-plane output routed per 16-col group (Q plane / K plane /
//         V^T key-permuted packed-8B scatter).  MODE 1: f32 + bias.
template <int NR, int MODE>
__global__ __launch_bounds__(512, 1) void gemm3b(const unsigned short* __restrict__ A,
                                                 const unsigned short* __restrict__ BT,
                                                 unsigned short* __restrict__ Cb,
                                                 float* __restrict__ Cf,
                                                 const float* __restrict__ bias,
                                                 int M, int N, int K) {
  constexpr int BN = NR * 64;
  __shared__ alignas(16) unsigned short As[3][256 * 64];
  __shared__ alignas(16) unsigned short Bs[2][BN * 64];

  const int nbn = N / BN;
  const int tmg = (M / 256) / 8;
  const int cc = blockIdx.x >> 3, xc = blockIdx.x & 7;
  const int tm = xc * tmg + cc / nbn, tn = cc % nbn;

  const int t = threadIdx.x, l = t & 63, wid = t >> 6;
  const int wm = wid >> 2, wn = wid & 3;
  const int lr = l & 15, lg = l >> 4;

  f32x4 acc[8][NR] = {};

  const int sq = t >> 3;
  const int sslot8 = ((t & 7) ^ (sq & 7)) * 8;
  const unsigned short* Ath = A + ((long)tm * 256 + sq) * K + sslot8;
  const unsigned short* Bth = BT + ((long)tn * BN + sq) * K + sslot8;
  const int ldsoff = sq * 64 + (t & 7) * 8;

#define STGA(buf, q, kt) \
  gload16(Ath + (long)((q)*64) * K + (kt)*64, &As[buf][(q)*4096 + ldsoff])
#define STGB(buf, u, kt) \
  gload16(Bth + (long)((u)*64) * K + (kt)*64, &Bs[buf][(u)*4096 + ldsoff])

  const int NT = K >> 6;
#pragma unroll
  for (int q = 0; q < 4; ++q) STGA(0, q, 0);
#pragma unroll
  for (int u = 0; u < NR; ++u) STGB(0, u, 0);
#pragma unroll
  for (int q = 0; q < 4; ++q) STGA(1, q, 1);

  const int offk0 = (lg ^ (lr & 7)) * 8;
  const int offk1 = ((4 + lg) ^ (lr & 7)) * 8;
  const int arow0 = (wm * 128 + lr) * 64;
  const int brow0 = (wn * (NR * 16) + lr) * 64;

#define DS_A(MH)                                                   \
  _Pragma("unroll") for (int m_ = 0; m_ < 4; ++m_) {               \
    const unsigned short* ap_ = Ac + arow0 + ((MH)*4 + m_) * 1024; \
    af[m_][0] = *(const bf16x8*)(ap_ + offk0);                     \
    af[m_][1] = *(const bf16x8*)(ap_ + offk1);                     \
  }
#define DS_B_ALL                                          \
  _Pragma("unroll") for (int n_ = 0; n_ < NR; ++n_) {     \
    const unsigned short* bp_ = Bc + brow0 + n_ * 1024;   \
    bfr[n_][0] = *(const bf16x8*)(bp_ + offk0);           \
    bfr[n_][1] = *(const bf16x8*)(bp_ + offk1);           \
  }
#define MM(MH)                                                              \
  __builtin_amdgcn_s_setprio(1);                                            \
  _Pragma("unroll") for (int m_ = 0; m_ < 4; ++m_)                          \
  _Pragma("unroll") for (int n_ = 0; n_ < NR; ++n_) {                       \
    acc[(MH)*4 + m_][n_] = MFMA16(af[m_][0], bfr[n_][0],                    \
                                  acc[(MH)*4 + m_][n_], 0, 0, 0);           \
    acc[(MH)*4 + m_][n_] = MFMA16(af[m_][1], bfr[n_][1],                    \
                                  acc[(MH)*4 + m_][n_], 0, 0, 0);           \
  }                                                                         \
  __builtin_amdgcn_s_setprio(0);

  int cur3 = 0;
  int stg3 = 2;
  for (int tt = 0; tt < NT; ++tt) {
    const unsigned short* Ac = As[cur3];
    const unsigned short* Bc = Bs[tt & 1];

    bf16x8 af[4][2];
    bf16x8 bfr[NR][2];

    if (tt == NT - 1) asm volatile("s_waitcnt vmcnt(0)" ::: "memory");
    else              asm volatile("s_waitcnt vmcnt(4)" ::: "memory");
    BARRIER;
    DS_A(0);
    DS_B_ALL;
    if (tt + 1 < NT) {
      const int nbB = (tt + 1) & 1;
#pragma unroll
      for (int u = 0; u < NR; ++u) STGB(nbB, u, tt + 1);
    }
    BARRIER;
    LGKM0;
    MM(0);

    DS_A(1);
    if (tt + 2 < NT) {
#pragma unroll
      for (int q = 0; q < 4; ++q) STGA(stg3, q, tt + 2);
    }
    BARRIER;
    LGKM0;
    MM(1);

    cur3 = (cur3 == 2) ? 0 : cur3 + 1;
    stg3 = (stg3 == 2) ? 0 : stg3 + 1;
  }
#undef DS_A
#undef DS_B_ALL
#undef MM
#undef STGA
#undef STGB

  const long crow = (long)tm * 256 + wm * 128;
  const int ccol = tn * BN + wn * (NR * 16);

  if constexpr (MODE == 1) {
#pragma unroll
    for (int m = 0; m < 8; ++m)
#pragma unroll
      for (int n = 0; n < NR; ++n)
#pragma unroll
        for (int r = 0; r < 4; ++r) {
          long row = crow + m * 16 + lg * 4 + r;
          int col = ccol + n * 16 + lr;
          Cf[row * N + col] = acc[m][n][r] + bias[col];
        }
  } else {
    // per-16-col-group plane routing (1024 % 16 == 0 -> group in one plane)
#pragma unroll
    for (int n = 0; n < NR; ++n) {
      const int colg = ccol + n * 16;  // wave-uniform
      const int plane = colg >> 10;
      if (plane < 2) {
        unsigned short* pl = Cb + (size_t)plane * 8388608;
        const int pc = (colg & 1023) + lr;
#pragma unroll
        for (int m = 0; m < 8; ++m)
#pragma unroll
          for (int r = 0; r < 4; ++r) {
            long row = crow + m * 16 + lg * 4 + r;
            pl[row * 1024 + pc] = f2bf(acc[m][n][r]);
          }
      } else {
        // V^T plane, key permutation: Vt[(b*16+h)*64+hd][2048 s-perm]
        unsigned short* VtW = Cb + 16777216;
        const int bq = (tm >> 3) << 4;
        const int sbase = ((tm & 7) << 8) + wm * 128;
        const int vcol = (colg & 1023) + lr;
        const long vtrow = (long)(bq + (vcol >> 6)) * 64 + (vcol & 63);
#pragma unroll
        for (int m = 0; m < 8; ++m) {
          const int srow_ = sbase + m * 16 + lg * 4;
          const int lwb = srow_ & 63;
          const int stt = srow_ >> 6;
          const int vp0 = (lwb & 32) | (((lwb >> 2) & 3) << 3) | (((lwb >> 4) & 1) << 2);
          unsigned long long pk4 =
              (unsigned long long)f2bf(acc[m][n][0]) |
              ((unsigned long long)f2bf(acc[m][n][1]) << 16) |
              ((unsigned long long)f2bf(acc[m][n][2]) << 32) |
              ((unsigned long long)f2bf(acc[m][n][3]) << 48);
          *(unsigned long long*)(VtW + vtrow * 2048 + stt * 64 + vp0) = pk4;
        }
      }
    }
  }
}

// ---------------- Flash attention tile body (static-max, scalar accum) ------
// Softmax is shift-invariant: P = exp2((s - SM_M)*C) with STATIC SM_M is
// exact.  Row-sum accumulates per-lane in plain float l_r (R12-proven
// reference pattern), reduced once across the 4-lane group in the epilogue.
template <int TWO>
__device__ __forceinline__ void attn_tile(
    const unsigned short* __restrict__ Kc, const unsigned short* __restrict__ Vc,
    int lr, int lg, bool mask0, bool mask1, int kv0, int q0row, int q1row,
    const bf16x8 (&qf)[2][2], f32x4 (&cacc)[2][4], float (&l_r)[2]) {
  constexpr int S0 = TWO ? 0 : 1;
  f32x4 p[2][4];
#pragma unroll
  for (int s = S0; s < 2; ++s)
#pragma unroll
    for (int g = 0; g < 4; ++g) p[s][g] = f32x4{0.f, 0.f, 0.f, 0.f};

  __builtin_amdgcn_s_setprio(1);
#pragma unroll
  for (int g = 0; g < 4; ++g) {
    const int key = g * 16 + lr;
    const int swz = (key & 7) << 3;
#pragma unroll
    for (int c = 0; c < 2; ++c) {
      bf16x8 kf = *(const bf16x8*)(Kc + key * 64 + ((c * 32 + lg * 8) ^ swz));
#pragma unroll
      for (int s = S0; s < 2; ++s)
        p[s][g] = MFMA16(kf, qf[s][c], p[s][g], 0, 0, 0);
    }
  }
  __builtin_amdgcn_s_setprio(0);

  if (TWO && mask0) {
#pragma unroll
    for (int g = 0; g < 4; ++g)
#pragma unroll
      for (int r = 0; r < 4; ++r)
        if (kv0 + g * 16 + lg * 4 + r > q0row) p[0][g][r] = -1e30f;
  }
  if (mask1) {
#pragma unroll
    for (int g = 0; g < 4; ++g)
#pragma unroll
      for (int r = 0; r < 4; ++r)
        if (kv0 + g * 16 + lg * 4 + r > q1row) p[1][g][r] = -1e30f;
  }

  const float SM_NMC = -SM_M * SM_C;
  unsigned pk[2][4][2];
#pragma unroll
  for (int s = S0; s < 2; ++s) {
    float e[4][4];
#pragma unroll
    for (int g = 0; g < 4; ++g)
#pragma unroll
      for (int r = 0; r < 4; ++r)
        e[g][r] = __builtin_amdgcn_exp2f(__builtin_fmaf(p[s][g][r], SM_C, SM_NMC));
    float t0 = (e[0][0] + e[0][1]) + (e[0][2] + e[0][3]);
    float t1 = (e[1][0] + e[1][1]) + (e[1][2] + e[1][3]);
    float t2 = (e[2][0] + e[2][1]) + (e[2][2] + e[2][3]);
    float t3 = (e[3][0] + e[3][1]) + (e[3][2] + e[3][3]);
    l_r[s] += (t0 + t1) + (t2 + t3);
#pragma unroll
    for (int g = 0; g < 4; ++g) {
      pk[s][g][0] = cvtpk(e[g][0], e[g][1]);
      pk[s][g][1] = cvtpk(e[g][2], e[g][3]);
    }
  }

#pragma unroll
  for (int sl = 0; sl < 2; ++sl) {
    bf16x8 vf[4];
#pragma unroll
    for (int n = 0; n < 4; ++n) {
      const int hd = n * 16 + lr;
      vf[n] = *(const bf16x8*)(Vc + hd * 64 + ((sl * 32 + lg * 8) ^ ((hd & 7) << 3)));
    }
    __builtin_amdgcn_s_setprio(1);
#pragma unroll
    for (int s = S0; s < 2; ++s) {
      uint4v pw = {pk[s][2 * sl][0], pk[s][2 * sl][1], pk[s][2 * sl + 1][0], pk[s][2 * sl + 1][1]};
      bf16x8 pa = __builtin_bit_cast(bf16x8, pw);
#pragma unroll
      for (int n = 0; n < 4; ++n)
        cacc[s][n] = MFMA16(pa, vf[n], cacc[s][n], 0, 0, 0);
    }
    __builtin_amdgcn_s_setprio(0);
  }
}

// ---------------- Flash attention (paired strips, counted-vmcnt pipeline) ---
__global__ __launch_bounds__(256, 4) void flash_attn(const unsigned short* __restrict__ Qp,
                                                     const unsigned short* __restrict__ Kp,
                                                     const unsigned short* __restrict__ Vt,
                                                     unsigned short* __restrict__ Ctx) {
  __shared__ alignas(16) unsigned short Ks[2][64 * 64];
  __shared__ alignas(16) unsigned short Vs[2][64 * 64];
  const int bid = blockIdx.x;
  const int qt = bid >> 6;
  const int bh = bid & 63;
  const int b = bh >> 4, h = bh & 15;
  const int t = threadIdx.x, l = t & 63, w = t >> 6;
  const int lr = l & 15, lg = l >> 4;
  const long rowbase = (long)b * 2048;
  const int colbase = h * 64;
  const int q0 = qt * 64 + w * 16;
  const int q1 = (31 - qt) * 64 + w * 16;
  const int q0row = q0 + lr, q1row = q1 + lr;
  const int nkv = 32 - qt;

  bf16x8 qf[2][2];
#pragma unroll
  for (int c = 0; c < 2; ++c) {
    qf[0][c] = *(const bf16x8*)(Qp + (rowbase + q0 + lr) * 1024 + colbase + c * 32 + lg * 8);
    qf[1][c] = *(const bf16x8*)(Qp + (rowbase + q1 + lr) * 1024 + colbase + c * 32 + lg * 8);
  }

  f32x4 cacc[2][4];
  float l_r[2];
#pragma unroll
  for (int s = 0; s < 2; ++s) {
    l_r[s] = 0.f;
#pragma unroll
    for (int n = 0; n < 4; ++n) cacc[s][n] = f32x4{0.f, 0.f, 0.f, 0.f};
  }

  const int srow = w * 16 + (l >> 3);
  const int scol = (l & 7) * 8;
  const int kswz = scol ^ ((srow & 7) << 3);
  const unsigned short* kp = Kp + (rowbase + srow) * 1024 + colbase + kswz;
  const unsigned short* vp = Vt + ((long)(bh * 64 + srow)) * 2048 + kswz;
  unsigned short* ksd0 = &Ks[0][(w * 16) * 64];
  unsigned short* vsd0 = &Vs[0][(w * 16) * 64];

#define STAGE(buf)                                    \
  do {                                                \
    gload16(kp, ksd0 + (buf) * 4096);                 \
    gload16(kp + 8 * 1024, ksd0 + (buf) * 4096 + 512);\
    gload16(vp, vsd0 + (buf) * 4096);                 \
    gload16(vp + 8 * 2048, vsd0 + (buf) * 4096 + 512);\
    kp += 64 * 1024;                                  \
    vp += 64;                                         \
  } while (0)

#define TILE_WAIT(j)                                                          \
  do {                                                                        \
    if ((j) == nkv - 1) asm volatile("s_waitcnt vmcnt(0)" ::: "memory");      \
    else                asm volatile("s_waitcnt vmcnt(4)" ::: "memory");      \
    asm volatile("s_barrier" ::: "memory");                                   \
  } while (0)

  STAGE(0);
  STAGE(1);

  int j = 0;
  for (; j <= qt; ++j) {  // both strips active
    const int cur = j & 1;
    TILE_WAIT(j);
    attn_tile<1>(Ks[cur], Vs[cur], lr, lg, j == qt, false, j * 64, q0row, q1row,
                 qf, cacc, l_r);
    asm volatile("s_barrier" ::: "memory");
    if (j + 2 < nkv) STAGE(cur);
  }
  for (; j < nkv; ++j) {  // long strip only
    const int cur = j & 1;
    TILE_WAIT(j);
    attn_tile<0>(Ks[cur], Vs[cur], lr, lg, false, j == nkv - 1, j * 64, q0row, q1row,
                 qf, cacc, l_r);
    asm volatile("s_barrier" ::: "memory");
    if (j + 2 < nkv) STAGE(cur);
  }
#undef STAGE
#undef TILE_WAIT

#pragma unroll
  for (int s = 0; s < 2; ++s) {
    float rs = l_r[s];
    rs += __shfl_xor(rs, 16);
    rs += __shfl_xor(rs, 32);
    float invl = 1.f / rs;
    float ilq[4];
#pragma unroll
    for (int r = 0; r < 4; ++r) ilq[r] = __shfl(invl, lg * 20 + r);
    const int qs = (s == 0) ? q0 : q1;
#pragma unroll
    for (int n = 0; n < 4; ++n)
#pragma unroll
      for (int r = 0; r < 4; ++r) {
        long row = rowbase + qs + lg * 4 + r;
        Ctx[row * 1024 + colbase + n * 16 + lr] = f2bf(cacc[s][n][r] * ilq[r]);
      }
  }
}

extern "C" void kernel_launch(void* const* d_in, const int* in_sizes, int n_in,
                              void* d_out, int out_size, void* d_ws, size_t ws_size,
                              hipStream_t stream) {
  (void)in_sizes; (void)n_in; (void)out_size; (void)ws_size;
  const float* x  = (const float*)d_in[0];
  const float* Wq = (const float*)d_in[1];
  const float* Wk = (const float*)d_in[2];
  const float* Wv = (const float*)d_in[3];
  const float* Wo = (const float*)d_in[4];
  const float* bo = (const float*)d_in[5];
  float* out = (float*)d_out;

  unsigned short* ws = (unsigned short*)d_ws;
  unsigned short* xb  = ws;                       // 8192*1024 bf16
  unsigned short* WqT = ws + 8388608;             // 4x 1024*1024 (Wq,Wk,Wv,Wo)
  unsigned short* WoT = WqT + 3145728;
  unsigned short* QKV = WqT + 4194304;            // 3 planes: Q | K | V^T (8M each)
  unsigned short* Qp  = QKV;
  unsigned short* Kp  = QKV + 8388608;
  unsigned short* Vt  = QKV + 16777216;
  unsigned short* Ctx = QKV + 25165824;           // 8192*1024

  cvt_x<<<2048, 256, 0, stream>>>(x, xb, 8192 * 1024 / 4);

  dim3 tb(32, 8), tg(32, 32, 4);
  transpose_w4<<<tg, tb, 0, stream>>>(Wq, Wk, Wv, Wo, WqT);

  // fused QKV projection: M=8192, N=3072, K=1024 (256x192 tiles, 512 blocks =
  // 2 exact rounds); outputs routed to Q / K / V^T planes in the epilogue.
  gemm3b<3, 0><<<512, 512, 0, stream>>>(xb, WqT, QKV, nullptr, nullptr,
                                        8192, 3072, 1024);

  // flash attention: 64 bh x 16 paired-strip blocks
  flash_attn<<<1024, 256, 0, stream>>>(Qp, Kp, Vt, Ctx);

  // output projection + bias: fp32 out (256x128 tiles, 256 blocks = 1 round)
  gemm3b<2, 1><<<256, 512, 0, stream>>>(Ctx, WoT, nullptr, out, bo,
                                        8192, 1024, 1024);
}